// Round 14
// baseline (63810.846 us; speedup 1.0000x reference)
//
#include <hip/hip_runtime.h>
#include <math.h>

#define NBLK    32          // worker blocks, all on ONE XCD (its 32 CUs)
#define NLAUNCH 256         // launched blocks; non-elected exit immediately
#define BS      512
#define NSTATE  17
#define NH      256
#define NX      273         // NH + NSTATE
#define WID     1024
#define NT      64
#define NSUB    8
#define POLL_CAP 500000     // fail fast instead of hanging

// packed partial word: {cnt:8 | (q0+B):28 | (q1+B):28}, q = round(p * 2^15)
// now 8 adds/word (W=128 stripes): 8*(q+B) <= 2^26 < 2^28, no field carry.
#define SCALE_P 32768.0f
#define INV_P   3.0517578125e-5f
#define BIAS_P  (1LL << 22)
#define BIAS8   (8LL << 22)
// dh running-total word: {cnt:16 | int48 value}, scale 2^20 (R12-proven)
#define SCALE_D 1048576.0f
#define INV_D   9.5367431640625e-7f

typedef unsigned long long u64;
typedef unsigned int u32;

__device__ __forceinline__ float softplus_f(float v) {
    return fmaxf(v, 0.f) + log1pf(expf(-fabsf(v)));
}

// ---- counter-embedded fixed-point accumulate exchange (same-XCD L2) -------
// R13 lesson: detect-loop s_sleep poisons latency (-30%); removed. R11-R13
// marginal analysis: stage time ~ 9us fixed + count/(17/cy); the fixed term
// is dominated by the per-word same-address RMW chain (was 32 serialized
// adds). R14: 128-col stripes -> 8 adds/word (chain 4x shorter), adds
// shfl-reduced 4:1 before touching L2. dh keeps R12's running-total form:
// its 32-adds/word IS the global fence the deferred parity resets rely on.
__device__ __forceinline__ void acc_pack(u64* p, float p0, float p1) {
    long long q0 = llrintf(p0 * SCALE_P) + BIAS_P;
    long long q1 = llrintf(p1 * SCALE_P) + BIAS_P;
    u64 w = 1ULL + ((u64)q0 << 8) + ((u64)q1 << 36);
    asm volatile("global_atomic_add_x2 %0, %1, off" :: "v"(p), "v"(w) : "memory");
}
__device__ __forceinline__ void acc_dh(u64* p, float v) {
    long long q = llrintf(v * SCALE_D);
    u64 w = ((u64)q << 16) + 1ULL;
    asm volatile("global_atomic_add_x2 %0, %1, off" :: "v"(p), "v"(w) : "memory");
}
__device__ __forceinline__ u64 rmw_read(const u64* p) {
    u64 w;
    asm volatile("global_atomic_add_x2 %0, %1, %2, off sc0\n\t"
                 "s_waitcnt vmcnt(0)"
                 : "=&v"(w) : "v"(p), "v"(0ULL) : "memory");
    return w;
}
__device__ __forceinline__ void reset_async(u64* p) {   // parity + fence safe
    asm volatile("global_atomic_swap_x2 %0, %1, off" :: "v"(p), "v"(0ULL) : "memory");
}
__device__ __forceinline__ u64 poll_cnt8(const u64* p) {
    u64 w; int it = 0;
    do { w = rmw_read(p); } while ((w & 0xFFu) != 8u && ++it < POLL_CAP);
    return w;
}

extern "C" __global__ __launch_bounds__(BS, 1) void ode_kernel(
    const float* __restrict__ ts,   const float* __restrict__ W0,
    const float* __restrict__ b0,   const float* __restrict__ Wh,
    const float* __restrict__ bh,   const float* __restrict__ Wl,
    const float* __restrict__ bl,   const float* __restrict__ betaW,
    const float* __restrict__ betab,const float* __restrict__ hvec,
    const float* __restrict__ scale,const float* __restrict__ y0log,
    float* __restrict__ out, u64* hacc1, u64* hacc2, u64* hacc3,
    u64* dhacc, unsigned* ctrl)
{
    const int t = threadIdx.x;

    __shared__ int role_sh;
    __shared__ __align__(16) float y_s[NX];
    __shared__ __align__(16) float yn_s[NX];
    __shared__ __align__(16) float xm[NX];    // MLP order: [h(256), state(17)]
    __shared__ __align__(16) float k_s[NX];
    __shared__ __align__(16) float z1_s[128];
    __shared__ __align__(16) float h1_s[128];
    __shared__ __align__(16) float h2_s[128];
    __shared__ __align__(16) float h3_s[128];
    __shared__ float red[8];
    __shared__ float dt_sh;
    extern __shared__ float lds_pad[];   // dummy 96KB: forces 1 block/CU
    (void)lds_pad;

    // ---- XCD election (MALL atomics, one-time): first XCD with NBLK blocks
    // wins. 96KB dyn LDS -> 1 block/CU; all 256 launched blocks co-resident.
    if (t == 0) {
        int xcd;
        asm volatile("s_getreg_b32 %0, hwreg(HW_REG_XCC_ID)" : "=s"(xcd));
        xcd &= 7;
        unsigned rk = atomicAdd(&ctrl[xcd], 1u);
        if (rk == NBLK - 1) atomicCAS(&ctrl[8], 0u, (unsigned)(xcd + 1));
        unsigned w; int it = 0;
        do {
            w = __hip_atomic_load(&ctrl[8], __ATOMIC_RELAXED, __HIP_MEMORY_SCOPE_AGENT);
        } while (w == 0u && ++it < 2000000);
        role_sh = (w != 0u && xcd == (int)w - 1 && rk < NBLK) ? (int)rk : -1;
    }
    __syncthreads();
    const int blk = role_sh;
    if (blk < 0) return;

    const float scale0 = scale[0];
    const float betab0 = betab[0];

    const int sb = blk >> 2;     // stripe: input cols [128*sb, +128)
    const int qb = blk & 3;      // quarter: output rows [256*qb, +256)

    // z1 roles: thread t -> row_l = t>>2 of [128*sb,+128), col subset t&3
    const int zrl = t >> 2, zc4 = t & 3;
    const float b0r = b0[128 * sb + zrl];
    const float* w0p = W0 + (size_t)(128 * sb + zrl) * NX;

    // h produce roles: group of 4 threads per word; word = 128*qb + (t>>2)
    const int pw   = t >> 2;
    const int widx = 128 * qb + pw;          // output packed-word index
    const int r0g  = 2 * widx;               // output rows r0g, r0g+1
    const int colg = 128 * sb + 32 * zc4;    // global input col base
    const int coll = 32 * zc4;               // local col base in *_s[128]
    const float* w1a = Wh + (size_t)r0g * WID + colg;
    const float* w1b = Wh + (size_t)(r0g + 1) * WID + colg;
    const float* w2a = w1a + (size_t)WID * WID;
    const float* w2b = w1b + (size_t)WID * WID;
    const float* w3a = w2a + (size_t)WID * WID;
    const float* w3b = w2b + (size_t)WID * WID;

    // consume biases (t<64): rows 128*sb + 2t, +1 of each layer
    float be[3], bo[3];
    if (t < 64) {
        be[0] = bh[128 * sb + 2 * t];            bo[0] = bh[128 * sb + 2 * t + 1];
        be[1] = bh[WID + 128 * sb + 2 * t];      bo[1] = bh[WID + 128 * sb + 2 * t + 1];
        be[2] = bh[2 * WID + 128 * sb + 2 * t];  bo[2] = bh[2 * WID + 128 * sb + 2 * t + 1];
    }
    // dh role (t<256): row t, cols [128*sb + 32*qb, +32)  (R12 geometry)
    const float* wlp = Wl + (size_t)t * WID + 128 * sb + 32 * qb;
    const float blr  = (t < NH) ? bl[t] : 0.f;
    const float betaWr = (t < NH) ? betaW[t] : 0.f;

    // ---- y0 = [softmax(y0_log), hvec] ----
    if (t < NSTATE) {
        float m = -1e30f;
        for (int j = 0; j < NSTATE; j++) m = fmaxf(m, y0log[j]);
        float ssum = 0.f;
        for (int j = 0; j < NSTATE; j++) ssum += expf(y0log[j] - m);
        y_s[t] = expf(y0log[t] - m) / ssum;
    }
    if (t < NH) y_s[NSTATE + t] = hvec[t];
    __syncthreads();

    if (blk == 0) {
        if (t < NSTATE) out[t] = y_s[t];
        if (t < NH)     out[NT * NSTATE + t] = y_s[NSTATE + t];
    }

    const float c_xi = 13.f / 12.f, c_mu = 0.041f / 12.f, c_sig = 91.f / 12.f,
                c_nu = 36.f / 12.f, c_gam = 1.8f / 12.f;

    long long prev_dh = 0;   // running-total tracker for dh word t (t<NH)
    unsigned sidx = 0;       // global stage counter

    for (int iv = 0; iv < NT - 1; iv++) {
        if (t == 0) dt_sh = (ts[iv + 1] - ts[iv]) * (1.f / NSUB);
        __syncthreads();
        const float dt = dt_sh;

        for (int sub = 0; sub < NSUB; sub++) {
            if (t < NX) yn_s[t] = y_s[t];

            for (int s = 0; s < 4; s++) {
                const float a   = (s == 0) ? 0.f : ((s == 3) ? 1.f : 0.5f);
                const float wgt = ((s == 0) || (s == 3)) ? dt * (1.f / 6.f) : dt * (1.f / 3.f);
                const float adt = a * dt;
                ++sidx;
                const int par = (int)(sidx & 1u);
                u64* h1p = hacc1 + par * 512;
                u64* h2p = hacc2 + par * 512;
                u64* h3p = hacc3 + par * 512;

                // ---- stage input, MLP order [h, state] ----
                if (t < NX) {
                    const int src = (t < NH) ? (NSTATE + t) : (t - NH);
                    float v = y_s[src];
                    if (s != 0) v = fmaf(adt, k_s[src], v);
                    xm[t] = v;
                }
                __syncthreads();                                   // B1

                // ---- z1: 128 stripe rows, redundant per stripe (no RMWs).
                //      4 threads/row, strided cols, shfl-reduce width 4.
                {
                    float acc = 0.f;
                    for (int i = 0; i < 69; i++) {
                        int c = zc4 + 4 * i;
                        if (c < NX) acc = fmaf(w0p[c], xm[c], acc);
                    }
                    acc += __shfl_xor(acc, 1, 4);
                    acc += __shfl_xor(acc, 2, 4);
                    if (zc4 == 0) z1_s[zrl] = softplus_f(acc + b0r);
                }
                if (t < NH) {      // beta head partial
                    float p = betaWr * xm[t];
                    #pragma unroll
                    for (int m = 1; m < 64; m <<= 1) p += __shfl_xor(p, m, 64);
                    if ((t & 63) == 0) red[t >> 6] = p;
                }
                __syncthreads();                                   // B2

                // ---- h1 produce: 2 rows x 32 cols per thread, 4:1 reduce ----
                {
                    float p0 = 0.f, p1 = 0.f;
                    #pragma unroll
                    for (int q = 0; q < 8; q++) {
                        float4 wa = *(const float4*)(w1a + 4 * q);
                        float4 wb = *(const float4*)(w1b + 4 * q);
                        float4 z  = *(const float4*)(z1_s + coll + 4 * q);
                        p0 = fmaf(wa.x, z.x, p0); p0 = fmaf(wa.y, z.y, p0);
                        p0 = fmaf(wa.z, z.z, p0); p0 = fmaf(wa.w, z.w, p0);
                        p1 = fmaf(wb.x, z.x, p1); p1 = fmaf(wb.y, z.y, p1);
                        p1 = fmaf(wb.z, z.z, p1); p1 = fmaf(wb.w, z.w, p1);
                    }
                    p0 += __shfl_xor(p0, 1, 4); p0 += __shfl_xor(p0, 2, 4);
                    p1 += __shfl_xor(p1, 1, 4); p1 += __shfl_xor(p1, 2, 4);
                    if (zc4 == 0) acc_pack(h1p + widx, p0, p1);
                }

                // ---- dstate (redundant, one thread; overlaps h1 flight) ----
                if (t == 256) {
                    const float* xs = xm + NH;
                    float sd  = red[0] + red[1] + red[2] + red[3] + betab0;
                    float bb1 = 8.f / (1.f + expf(-sd)) + 25.f;
                    float bb2 = 0.5f * bb1, bb3 = 0.35f * bb1, bb4 = 0.25f * bb1;
                    float M  = xs[0],  S1 = xs[1],  E1 = xs[2],  E2 = xs[3];
                    float E3 = xs[4],  E4 = xs[5],  I1 = xs[6],  I2 = xs[7];
                    float I3 = xs[8],  I4 = xs[9],  R1 = xs[10], R2 = xs[11];
                    float R3 = xs[12], R4 = xs[13], S2 = xs[14], S3 = xs[15];
                    float S4 = xs[16];
                    float I = I1 + I2 + I3 + I4, Rs = R1 + R2 + R3 + R4;
                    k_s[0]  = Rs * c_mu - (c_xi + c_mu) * M;
                    k_s[1]  = c_mu * (1.f - Rs) + c_xi * M - c_mu * S1 - bb1 * I * S1;
                    k_s[2]  = bb1 * I * S1 - (c_mu + c_sig) * E1;
                    k_s[3]  = bb2 * I * S2 - (c_mu + c_sig) * E2;
                    k_s[4]  = bb3 * I * S3 - (c_mu + c_sig) * E3;
                    k_s[5]  = bb4 * I * S4 - (c_mu + c_sig) * E4;
                    k_s[6]  = c_sig * E1 - (c_nu + c_mu) * I1;
                    k_s[7]  = c_sig * E2 - (c_nu + c_mu) * I2;
                    k_s[8]  = c_sig * E3 - (c_nu + c_mu) * I3;
                    k_s[9]  = c_sig * E4 - (c_nu + c_mu) * I4;
                    k_s[10] = c_nu * I1 - (c_mu + c_gam) * R1;
                    k_s[11] = c_nu * I2 - (c_mu + c_gam) * R2;
                    k_s[12] = c_nu * I3 - (c_mu + c_gam) * R3;
                    k_s[13] = c_nu * I4 - (c_mu + c_gam) * R4;
                    k_s[14] = c_gam * R1 - c_mu * S2 - bb2 * I * S2;
                    k_s[15] = c_gam * R2 - c_mu * S3 - bb3 * I * S3;
                    k_s[16] = c_gam * (R3 + R4) - c_mu * S4 - bb4 * I * S4;
                }

                // ---- h1 consume: 64 stripe words, count==8 -> unpack ----
                if (t < 64) {
                    u64 w = poll_cnt8(h1p + 64 * sb + t);
                    long long v0 = (long long)((w >> 8) & 0xFFFFFFFULL) - BIAS8;
                    long long v1 = (long long)(w >> 36) - BIAS8;
                    h1_s[2 * t]     = softplus_f((float)v0 * INV_P + be[0]);
                    h1_s[2 * t + 1] = softplus_f((float)v1 * INV_P + bo[0]);
                }
                __syncthreads();                                   // B3

                // ---- h2 produce + consume ----
                {
                    float p0 = 0.f, p1 = 0.f;
                    #pragma unroll
                    for (int q = 0; q < 8; q++) {
                        float4 wa = *(const float4*)(w2a + 4 * q);
                        float4 wb = *(const float4*)(w2b + 4 * q);
                        float4 z  = *(const float4*)(h1_s + coll + 4 * q);
                        p0 = fmaf(wa.x, z.x, p0); p0 = fmaf(wa.y, z.y, p0);
                        p0 = fmaf(wa.z, z.z, p0); p0 = fmaf(wa.w, z.w, p0);
                        p1 = fmaf(wb.x, z.x, p1); p1 = fmaf(wb.y, z.y, p1);
                        p1 = fmaf(wb.z, z.z, p1); p1 = fmaf(wb.w, z.w, p1);
                    }
                    p0 += __shfl_xor(p0, 1, 4); p0 += __shfl_xor(p0, 2, 4);
                    p1 += __shfl_xor(p1, 1, 4); p1 += __shfl_xor(p1, 2, 4);
                    if (zc4 == 0) acc_pack(h2p + widx, p0, p1);
                }
                if (t < 64) {
                    u64 w = poll_cnt8(h2p + 64 * sb + t);
                    long long v0 = (long long)((w >> 8) & 0xFFFFFFFULL) - BIAS8;
                    long long v1 = (long long)(w >> 36) - BIAS8;
                    h2_s[2 * t]     = softplus_f((float)v0 * INV_P + be[1]);
                    h2_s[2 * t + 1] = softplus_f((float)v1 * INV_P + bo[1]);
                }
                __syncthreads();                                   // B4

                // ---- h3 produce + consume ----
                {
                    float p0 = 0.f, p1 = 0.f;
                    #pragma unroll
                    for (int q = 0; q < 8; q++) {
                        float4 wa = *(const float4*)(w3a + 4 * q);
                        float4 wb = *(const float4*)(w3b + 4 * q);
                        float4 z  = *(const float4*)(h2_s + coll + 4 * q);
                        p0 = fmaf(wa.x, z.x, p0); p0 = fmaf(wa.y, z.y, p0);
                        p0 = fmaf(wa.z, z.z, p0); p0 = fmaf(wa.w, z.w, p0);
                        p1 = fmaf(wb.x, z.x, p1); p1 = fmaf(wb.y, z.y, p1);
                        p1 = fmaf(wb.z, z.z, p1); p1 = fmaf(wb.w, z.w, p1);
                    }
                    p0 += __shfl_xor(p0, 1, 4); p0 += __shfl_xor(p0, 2, 4);
                    p1 += __shfl_xor(p1, 1, 4); p1 += __shfl_xor(p1, 2, 4);
                    if (zc4 == 0) acc_pack(h3p + widx, p0, p1);
                }
                if (t < 64) {
                    u64 w = poll_cnt8(h3p + 64 * sb + t);
                    long long v0 = (long long)((w >> 8) & 0xFFFFFFFULL) - BIAS8;
                    long long v1 = (long long)(w >> 36) - BIAS8;
                    h3_s[2 * t]     = softplus_f((float)v0 * INV_P + be[2]);
                    h3_s[2 * t + 1] = softplus_f((float)v1 * INV_P + bo[2]);
                }
                __syncthreads();                                   // B5

                // ---- dh: adds (t<256, 32-col slice) + running-total gather.
                //      32 adds/word = the GLOBAL FENCE for the parity resets.
                if (t < NH) {
                    float p = 0.f;
                    #pragma unroll
                    for (int q = 0; q < 8; q++) {
                        float4 wv = *(const float4*)(wlp + 4 * q);
                        float4 z  = *(const float4*)(h3_s + 32 * qb + 4 * q);
                        p = fmaf(wv.x, z.x, p); p = fmaf(wv.y, z.y, p);
                        p = fmaf(wv.z, z.z, p); p = fmaf(wv.w, z.w, p);
                    }
                    acc_dh(dhacc + t, p);

                    const u32 tgt = (32u * sidx) & 0xFFFFu;
                    u64 w; int it = 0;
                    do { w = rmw_read(dhacc + t); }
                    while ((u32)(w & 0xFFFFu) != tgt && ++it < POLL_CAP);
                    long long val = ((long long)w) >> 16;
                    long long diff = val - prev_dh;
                    prev_dh = val;
                    k_s[NSTATE + t] = scale0 * tanhf(0.01f * ((float)diff * INV_D + blr));
                }
                // deferred parity resets (post-fence; drained by next-stage
                // vmcnt chains before any possible reuse at s+2)
                if (t < 16) {
                    const int rw = 64 * sb + 16 * qb + t;
                    reset_async(h1p + rw);
                    reset_async(h2p + rw);
                    reset_async(h3p + rw);
                }
                __syncthreads();                                   // B6
                if (t < NX) yn_s[t] = fmaf(wgt, k_s[t], yn_s[t]);
            } // stages

            __syncthreads();
            if (t < NX) y_s[t] = yn_s[t];
            __syncthreads();
        } // substeps

        if (blk == 0) {
            if (t < NSTATE) out[(iv + 1) * NSTATE + t] = y_s[t];
            if (t < NH)     out[NT * NSTATE + (iv + 1) * NH + t] = y_s[NSTATE + t];
        }
    } // intervals
}

extern "C" void kernel_launch(void* const* d_in, const int* in_sizes, int n_in,
                              void* d_out, int out_size, void* d_ws, size_t ws_size,
                              hipStream_t stream) {
    const float* ts    = (const float*)d_in[0];
    const float* W0    = (const float*)d_in[1];
    const float* b0    = (const float*)d_in[2];
    const float* Wh    = (const float*)d_in[3];
    const float* bh    = (const float*)d_in[4];
    const float* Wl    = (const float*)d_in[5];
    const float* bl    = (const float*)d_in[6];
    const float* betaW = (const float*)d_in[7];
    const float* betab = (const float*)d_in[8];
    const float* hvec  = (const float*)d_in[9];
    const float* scale = (const float*)d_in[10];
    const float* y0log = (const float*)d_in[11];
    float* out = (float*)d_out;

    u64*      hacc1 = (u64*)d_ws;                         // 2x512 u64 = 8 KB
    u64*      hacc2 = (u64*)((char*)d_ws + 8192);         // 8 KB
    u64*      hacc3 = (u64*)((char*)d_ws + 16384);        // 8 KB
    u64*      dhacc = (u64*)((char*)d_ws + 24576);        // 256 u64 = 2 KB
    unsigned* ctrl  = (unsigned*)((char*)d_ws + 26624);   // cnt[8], winner

    // dummy 96KB dynamic LDS keeps 1 block/CU (election geometry)
    static int lds_set = 0;
    if (!lds_set) {
        hipFuncSetAttribute((const void*)ode_kernel,
                            hipFuncAttributeMaxDynamicSharedMemorySize, 98304);
        lds_set = 1;
    }

    // zero accumulators + counters + election state
    hipMemsetAsync(d_ws, 0, 26624 + 64, stream);
    hipLaunchKernelGGL(ode_kernel, dim3(NLAUNCH), dim3(BS), 98304, stream,
                       ts, W0, b0, Wh, bh, Wl, bl, betaW, betab, hvec, scale,
                       y0log, out, hacc1, hacc2, hacc3, dhacc, ctrl);
}

// Round 15
// 21026.442 us; speedup vs baseline: 3.0348x; 3.0348x over previous
//
#include <hip/hip_runtime.h>
#include <math.h>

#define NBLK    32          // worker blocks, all on ONE XCD (its 32 CUs)
#define NLAUNCH 256         // launched blocks; non-elected exit immediately
#define BS      512
#define NSTATE  17
#define NH      256
#define NX      273         // NH + NSTATE
#define WID     1024
#define NT      64
#define NSUB    8
#define SLC     32          // activation slice per block = WID/NBLK
#define POLL_CAP 500000     // fail fast instead of hanging

// packed partial word: {cnt:8 | (q0+B):28 | (q1+B):28}, q = round(p * 2^15)
// 28-bit field holds exactly 32 adds of (q+B), B=2^22, |q|<2^19 -- proven R12.
#define SCALE_P 32768.0f
#define INV_P   3.0517578125e-5f
#define BIAS_P  (1LL << 22)
#define BIAS32  (32LL << 22)

typedef unsigned long long u64;
typedef unsigned int u32;

__device__ __forceinline__ float softplus_f(float v) {
    return fmaxf(v, 0.f) + log1pf(expf(-fabsf(v)));
}

// ---- counter-embedded fixed-point accumulate exchange (same-XCD L2) -------
// Col-parallel partial sums through the L2 atomic units (never stale,
// R5-R12-proven; int adds associative -> deterministic, absmax exact).
// R12 = proven best (21.1ms). R14 lesson: weight residency (h1/h2 in exactly
// 128 VGPRs, h3 in LDS) is a hard precondition -- Wh (12MB) > L2 (4MB).
// R15 = R12 + packed dh ONLY: dh words halve (256->128) via the same packed
// 2-row format + parity double-buffer; deferred reset of prev-parity dh
// during next stage's h1-consume (h1 cnt==32 = global fence: all blocks
// finished last stage's dh reads). NO s_sleep (R13 lesson). NO extra Wl
// registers: row-pair formed by width-2 shfl, even threads add.
__device__ __forceinline__ void acc_pack(u64* p, float p0, float p1) {
    long long q0 = llrintf(p0 * SCALE_P) + BIAS_P;
    long long q1 = llrintf(p1 * SCALE_P) + BIAS_P;
    u64 w = 1ULL + ((u64)q0 << 8) + ((u64)q1 << 36);
    asm volatile("global_atomic_add_x2 %0, %1, off" :: "v"(p), "v"(w) : "memory");
}
__device__ __forceinline__ u64 rmw_read(const u64* p) {
    u64 w;
    asm volatile("global_atomic_add_x2 %0, %1, %2, off sc0\n\t"
                 "s_waitcnt vmcnt(0)"
                 : "=&v"(w) : "v"(p), "v"(0ULL) : "memory");
    return w;
}
__device__ __forceinline__ void reset_async(u64* p) {   // no fence: parity-safe
    asm volatile("global_atomic_swap_x2 %0, %1, off" :: "v"(p), "v"(0ULL) : "memory");
}
__device__ __forceinline__ u64 poll32(const u64* p) {   // cnt==32, NO sleep
    u64 w; int it = 0;
    do { w = rmw_read(p); } while ((w & 0xFFu) != 32u && ++it < POLL_CAP);
    return w;
}

extern "C" __global__ __launch_bounds__(BS, 1) void ode_kernel(
    const float* __restrict__ ts,   const float* __restrict__ W0,
    const float* __restrict__ b0,   const float* __restrict__ Wh,
    const float* __restrict__ bh,   const float* __restrict__ Wl,
    const float* __restrict__ bl,   const float* __restrict__ betaW,
    const float* __restrict__ betab,const float* __restrict__ hvec,
    const float* __restrict__ scale,const float* __restrict__ y0log,
    float* __restrict__ out, u64* hacc1, u64* hacc2, u64* hacc3,
    u64* dhacc, unsigned* ctrl)
{
    const int t = threadIdx.x;

    __shared__ int role_sh;
    __shared__ __align__(16) float y_s[NX];
    __shared__ __align__(16) float yn_s[NX];
    __shared__ __align__(16) float xm[NX];    // MLP order: [h(256), state(17)]
    __shared__ __align__(16) float k_s[NX];
    __shared__ __align__(16) float z1_s[SLC];
    __shared__ __align__(16) float h1_s[SLC];
    __shared__ __align__(16) float h2_s[SLC];
    __shared__ __align__(16) float h3_s[SLC];
    __shared__ float red[8];
    __shared__ float dt_sh;
    extern __shared__ float wh3c[];  // 128KB: col-major [j][r] = Wh[2][r][blk*32+j]

    // ---- XCD election (MALL atomics, one-time): first XCD with NBLK blocks
    // wins. ~134KB LDS -> 1 block/CU; all 256 launched blocks co-resident.
    if (t == 0) {
        int xcd;
        asm volatile("s_getreg_b32 %0, hwreg(HW_REG_XCC_ID)" : "=s"(xcd));
        xcd &= 7;
        unsigned rk = atomicAdd(&ctrl[xcd], 1u);
        if (rk == NBLK - 1) atomicCAS(&ctrl[8], 0u, (unsigned)(xcd + 1));
        unsigned w; int it = 0;
        do {
            w = __hip_atomic_load(&ctrl[8], __ATOMIC_RELAXED, __HIP_MEMORY_SCOPE_AGENT);
        } while (w == 0u && ++it < 2000000);
        role_sh = (w != 0u && xcd == (int)w - 1 && rk < NBLK) ? (int)rk : -1;
    }
    __syncthreads();
    const int blk = role_sh;
    if (blk < 0) return;

    const float scale0 = scale[0];
    const float betab0 = betab[0];

    const int rowH = t >> 4, laneH = t & 15;   // 32 rows x 16 lanes (z1 only)
    const int growH = blk * SLC + rowH;
    const int r0 = 2 * t, r1 = 2 * t + 1;      // packed output-row pair

    // ---- loop-invariant scalars ----
    const float b0r    = b0[growH];
    const float betaWr = (t < NH) ? betaW[t] : 0.f;
    float bl0 = 0.f, bl1 = 0.f;                // dh biases for rows 2t, 2t+1
    if (t < 128) { bl0 = bl[2 * t]; bl1 = bl[2 * t + 1]; }
    float bhc[3], bhc_o[3];
    if (t < 16) {
        bhc[0]   = bh[blk * SLC + 2 * t];
        bhc_o[0] = bh[blk * SLC + 2 * t + 1];
        bhc[1]   = bh[WID + blk * SLC + 2 * t];
        bhc_o[1] = bh[WID + blk * SLC + 2 * t + 1];
        bhc[2]   = bh[2 * WID + blk * SLC + 2 * t];
        bhc_o[2] = bh[2 * WID + blk * SLC + 2 * t + 1];
    }

    // ---- weights ----
    float w0r[18];     // W0 row-slice (z1 local)
    {
        const float* w0p = W0 + (size_t)growH * NX;
        #pragma unroll
        for (int i = 0; i < 18; i++) {
            int c = laneH + i * 16;
            w0r[i] = (c < NX) ? w0p[c] : 0.f;
        }
    }
    // h1/h2 COLUMN stripes in VGPRs: thread t owns rows {2t, 2t+1},
    // cols [blk*32,+32): 4x8 float4 = exactly 128 VGPR (residency-critical).
    float4 wc1a[8], wc1b[8], wc2a[8], wc2b[8];
    {
        const float* base0 = Wh + (size_t)r0 * WID + blk * SLC;
        const float* base1 = Wh + (size_t)r1 * WID + blk * SLC;
        #pragma unroll
        for (int q = 0; q < 8; q++) {
            wc1a[q] = *(const float4*)(base0 + q * 4);
            wc1b[q] = *(const float4*)(base1 + q * 4);
            wc2a[q] = *(const float4*)(base0 + (size_t)WID * WID + q * 4);
            wc2b[q] = *(const float4*)(base1 + (size_t)WID * WID + q * 4);
        }
    }
    // h3 column stripe in LDS, col-major [j][r]
    {
        const float* src = Wh + 2 * (size_t)WID * WID;
        for (int i = t; i < WID * 8; i += BS) {
            int r = i >> 3, q = i & 7;
            float4 v = *(const float4*)(src + (size_t)r * WID + blk * SLC + q * 4);
            wh3c[(q * 4 + 0) * WID + r] = v.x;
            wh3c[(q * 4 + 1) * WID + r] = v.y;
            wh3c[(q * 4 + 2) * WID + r] = v.z;
            wh3c[(q * 4 + 3) * WID + r] = v.w;
        }
    }

    // ---- y0 = [softmax(y0_log), hvec] ----
    if (t < NSTATE) {
        float m = -1e30f;
        for (int j = 0; j < NSTATE; j++) m = fmaxf(m, y0log[j]);
        float ssum = 0.f;
        for (int j = 0; j < NSTATE; j++) ssum += expf(y0log[j] - m);
        y_s[t] = expf(y0log[t] - m) / ssum;
    }
    if (t < NH) y_s[NSTATE + t] = hvec[t];
    __syncthreads();

    if (blk == 0) {
        if (t < NSTATE) out[t] = y_s[t];
        if (t < NH)     out[NT * NSTATE + t] = y_s[NSTATE + t];
    }

    const float c_xi = 13.f / 12.f, c_mu = 0.041f / 12.f, c_sig = 91.f / 12.f,
                c_nu = 36.f / 12.f, c_gam = 1.8f / 12.f;

    unsigned sidx = 0;       // global stage counter (parity selector)

    for (int iv = 0; iv < NT - 1; iv++) {
        if (t == 0) dt_sh = (ts[iv + 1] - ts[iv]) * (1.f / NSUB);
        __syncthreads();
        const float dt = dt_sh;

        for (int sub = 0; sub < NSUB; sub++) {
            if (t < NX) yn_s[t] = y_s[t];

            for (int s = 0; s < 4; s++) {
                const float a   = (s == 0) ? 0.f : ((s == 3) ? 1.f : 0.5f);
                const float wgt = ((s == 0) || (s == 3)) ? dt * (1.f / 6.f) : dt * (1.f / 3.f);
                const float adt = a * dt;
                ++sidx;
                const int par = (int)(sidx & 1u);       // parity buffer select
                u64* h1p = hacc1 + par * 512;
                u64* h2p = hacc2 + par * 512;
                u64* h3p = hacc3 + par * 512;
                u64* dhp = dhacc + par * 128;
                u64* dhq = dhacc + (par ^ 1) * 128;     // prev parity (reset)

                // ---- stage input, built directly in MLP order [h, state] ----
                if (t < NX) {
                    const int src = (t < NH) ? (NSTATE + t) : (t - NH);
                    float v = y_s[src];
                    if (s != 0) v = fmaf(adt, k_s[src], v);
                    xm[t] = v;
                }
                __syncthreads();                                   // B1

                // ---- z1 slice (local): 32 rows x 16 lanes ----
                {
                    float acc = 0.f;
                    #pragma unroll
                    for (int i = 0; i < 18; i++) {
                        int c = laneH + i * 16;
                        if (c < NX) acc = fmaf(w0r[i], xm[c], acc);
                    }
                    #pragma unroll
                    for (int m = 1; m < 16; m <<= 1) acc += __shfl_xor(acc, m, 16);
                    if (laneH == 0) z1_s[rowH] = softplus_f(acc + b0r);
                }
                if (t < NH) {      // beta head partial
                    float p = betaWr * xm[t];
                    #pragma unroll
                    for (int m = 1; m < 64; m <<= 1) p += __shfl_xor(p, m, 64);
                    if ((t & 63) == 0) red[t >> 6] = p;
                }
                __syncthreads();                                   // B2

                // ---- h1 packed partial adds (fire-and-forget) ----
                {
                    float p0 = 0.f, p1 = 0.f;
                    #pragma unroll
                    for (int q = 0; q < 8; q++) {
                        float4 z = *(const float4*)(z1_s + q * 4);
                        p0 = fmaf(wc1a[q].x, z.x, p0); p0 = fmaf(wc1a[q].y, z.y, p0);
                        p0 = fmaf(wc1a[q].z, z.z, p0); p0 = fmaf(wc1a[q].w, z.w, p0);
                        p1 = fmaf(wc1b[q].x, z.x, p1); p1 = fmaf(wc1b[q].y, z.y, p1);
                        p1 = fmaf(wc1b[q].z, z.z, p1); p1 = fmaf(wc1b[q].w, z.w, p1);
                    }
                    acc_pack(h1p + t, p0, p1);
                }

                // ---- dstate (redundant, one thread; overlaps h1 flight) ----
                if (t == 256) {
                    const float* xs = xm + NH;
                    float sd  = red[0] + red[1] + red[2] + red[3] + betab0;
                    float bb1 = 8.f / (1.f + expf(-sd)) + 25.f;
                    float bb2 = 0.5f * bb1, bb3 = 0.35f * bb1, bb4 = 0.25f * bb1;
                    float M  = xs[0],  S1 = xs[1],  E1 = xs[2],  E2 = xs[3];
                    float E3 = xs[4],  E4 = xs[5],  I1 = xs[6],  I2 = xs[7];
                    float I3 = xs[8],  I4 = xs[9],  R1 = xs[10], R2 = xs[11];
                    float R3 = xs[12], R4 = xs[13], S2 = xs[14], S3 = xs[15];
                    float S4 = xs[16];
                    float I = I1 + I2 + I3 + I4, Rs = R1 + R2 + R3 + R4;
                    k_s[0]  = Rs * c_mu - (c_xi + c_mu) * M;
                    k_s[1]  = c_mu * (1.f - Rs) + c_xi * M - c_mu * S1 - bb1 * I * S1;
                    k_s[2]  = bb1 * I * S1 - (c_mu + c_sig) * E1;
                    k_s[3]  = bb2 * I * S2 - (c_mu + c_sig) * E2;
                    k_s[4]  = bb3 * I * S3 - (c_mu + c_sig) * E3;
                    k_s[5]  = bb4 * I * S4 - (c_mu + c_sig) * E4;
                    k_s[6]  = c_sig * E1 - (c_nu + c_mu) * I1;
                    k_s[7]  = c_sig * E2 - (c_nu + c_mu) * I2;
                    k_s[8]  = c_sig * E3 - (c_nu + c_mu) * I3;
                    k_s[9]  = c_sig * E4 - (c_nu + c_mu) * I4;
                    k_s[10] = c_nu * I1 - (c_mu + c_gam) * R1;
                    k_s[11] = c_nu * I2 - (c_mu + c_gam) * R2;
                    k_s[12] = c_nu * I3 - (c_mu + c_gam) * R3;
                    k_s[13] = c_nu * I4 - (c_mu + c_gam) * R4;
                    k_s[14] = c_gam * R1 - c_mu * S2 - bb2 * I * S2;
                    k_s[15] = c_gam * R2 - c_mu * S3 - bb3 * I * S3;
                    k_s[16] = c_gam * (R3 + R4) - c_mu * S4 - bb4 * I * S4;
                }

                // ---- h1 consume + deferred dh reset of prev parity ----
                if (t < 16) {
                    u64* p = h1p + blk * 16 + t;
                    u64 w = poll32(p);
                    reset_async(p);
                    // h1 cnt==32 => all blocks finished last stage's dh reads
                    if (t < 4) reset_async(dhq + blk * 4 + t);
                    long long v0 = (long long)((w >> 8) & 0xFFFFFFFULL) - BIAS32;
                    long long v1 = (long long)(w >> 36) - BIAS32;
                    h1_s[2 * t]     = softplus_f((float)v0 * INV_P + bhc[0]);
                    h1_s[2 * t + 1] = softplus_f((float)v1 * INV_P + bhc_o[0]);
                }
                __syncthreads();                                   // B3

                // ---- h2 packed adds + consume ----
                {
                    float p0 = 0.f, p1 = 0.f;
                    #pragma unroll
                    for (int q = 0; q < 8; q++) {
                        float4 z = *(const float4*)(h1_s + q * 4);
                        p0 = fmaf(wc2a[q].x, z.x, p0); p0 = fmaf(wc2a[q].y, z.y, p0);
                        p0 = fmaf(wc2a[q].z, z.z, p0); p0 = fmaf(wc2a[q].w, z.w, p0);
                        p1 = fmaf(wc2b[q].x, z.x, p1); p1 = fmaf(wc2b[q].y, z.y, p1);
                        p1 = fmaf(wc2b[q].z, z.z, p1); p1 = fmaf(wc2b[q].w, z.w, p1);
                    }
                    acc_pack(h2p + t, p0, p1);
                }
                if (t < 16) {
                    u64* p = h2p + blk * 16 + t;
                    u64 w = poll32(p);
                    reset_async(p);
                    long long v0 = (long long)((w >> 8) & 0xFFFFFFFULL) - BIAS32;
                    long long v1 = (long long)(w >> 36) - BIAS32;
                    h2_s[2 * t]     = softplus_f((float)v0 * INV_P + bhc[1]);
                    h2_s[2 * t + 1] = softplus_f((float)v1 * INV_P + bhc_o[1]);
                }
                __syncthreads();                                   // B4

                // ---- h3 packed adds (weights from LDS, col-major) ----
                {
                    float p0 = 0.f, p1 = 0.f;
                    #pragma unroll
                    for (int j = 0; j < SLC; j++) {
                        float hv = h2_s[j];
                        float2 wv = *(const float2*)(wh3c + j * WID + r0);
                        p0 = fmaf(wv.x, hv, p0);
                        p1 = fmaf(wv.y, hv, p1);
                    }
                    acc_pack(h3p + t, p0, p1);
                }
                // Wl stripe prefetch (t<256): row t, cols [blk*32,+32) — as R12
                float4 wvL[8];
                if (t < NH) {
                    const float* wp = Wl + (size_t)t * WID + blk * SLC;
                    #pragma unroll
                    for (int q = 0; q < 8; q++) wvL[q] = *(const float4*)(wp + q * 4);
                }
                if (t < 16) {
                    u64* p = h3p + blk * 16 + t;
                    u64 w = poll32(p);
                    reset_async(p);
                    long long v0 = (long long)((w >> 8) & 0xFFFFFFFULL) - BIAS32;
                    long long v1 = (long long)(w >> 36) - BIAS32;
                    h3_s[2 * t]     = softplus_f((float)v0 * INV_P + bhc[2]);
                    h3_s[2 * t + 1] = softplus_f((float)v1 * INV_P + bhc_o[2]);
                }
                __syncthreads();                                   // B5

                // ---- dh: per-row partials (t<256, R12 layout), pair-merged
                //      via width-2 shfl, even threads issue the packed add ----
                if (t < NH) {
                    float p = 0.f;
                    #pragma unroll
                    for (int q = 0; q < 8; q++) {
                        float4 z = *(const float4*)(h3_s + q * 4);
                        p = fmaf(wvL[q].x, z.x, p); p = fmaf(wvL[q].y, z.y, p);
                        p = fmaf(wvL[q].z, z.z, p); p = fmaf(wvL[q].w, z.w, p);
                    }
                    float po = __shfl_xor(p, 1, 2);      // partner row's partial
                    if ((t & 1) == 0) acc_pack(dhp + (t >> 1), p, po);
                }
                // consume: t<128 polls its packed word (cnt==32), unpacks both
                if (t < 128) {
                    u64 w = poll32(dhp + t);
                    long long v0 = (long long)((w >> 8) & 0xFFFFFFFULL) - BIAS32;
                    long long v1 = (long long)(w >> 36) - BIAS32;
                    float a0 = (float)v0 * INV_P, a1 = (float)v1 * INV_P;
                    k_s[NSTATE + 2 * t]     = scale0 * tanhf(0.01f * (a0 + bl0));
                    k_s[NSTATE + 2 * t + 1] = scale0 * tanhf(0.01f * (a1 + bl1));
                }
                __syncthreads();                                   // B6
                if (t < NX) yn_s[t] = fmaf(wgt, k_s[t], yn_s[t]);
            } // stages

            __syncthreads();
            if (t < NX) y_s[t] = yn_s[t];
            __syncthreads();
        } // substeps

        if (blk == 0) {
            if (t < NSTATE) out[(iv + 1) * NSTATE + t] = y_s[t];
            if (t < NH)     out[NT * NSTATE + (iv + 1) * NH + t] = y_s[NSTATE + t];
        }
    } // intervals
}

extern "C" void kernel_launch(void* const* d_in, const int* in_sizes, int n_in,
                              void* d_out, int out_size, void* d_ws, size_t ws_size,
                              hipStream_t stream) {
    const float* ts    = (const float*)d_in[0];
    const float* W0    = (const float*)d_in[1];
    const float* b0    = (const float*)d_in[2];
    const float* Wh    = (const float*)d_in[3];
    const float* bh    = (const float*)d_in[4];
    const float* Wl    = (const float*)d_in[5];
    const float* bl    = (const float*)d_in[6];
    const float* betaW = (const float*)d_in[7];
    const float* betab = (const float*)d_in[8];
    const float* hvec  = (const float*)d_in[9];
    const float* scale = (const float*)d_in[10];
    const float* y0log = (const float*)d_in[11];
    float* out = (float*)d_out;

    // parity-doubled packed accumulators
    u64*      hacc1 = (u64*)d_ws;                         // 2x512 u64 = 8 KB
    u64*      hacc2 = (u64*)((char*)d_ws + 8192);         // 8 KB
    u64*      hacc3 = (u64*)((char*)d_ws + 16384);        // 8 KB
    u64*      dhacc = (u64*)((char*)d_ws + 24576);        // 2x128 u64 = 2 KB
    unsigned* ctrl  = (unsigned*)((char*)d_ws + 26624);   // cnt[8], winner

    // allow 128KB dynamic LDS (h3 column-stripe weights)
    static int lds_set = 0;
    if (!lds_set) {
        hipFuncSetAttribute((const void*)ode_kernel,
                            hipFuncAttributeMaxDynamicSharedMemorySize, 131072);
        lds_set = 1;
    }

    // zero accumulators + counters + election state
    hipMemsetAsync(d_ws, 0, 26624 + 64, stream);
    hipLaunchKernelGGL(ode_kernel, dim3(NLAUNCH), dim3(BS), 131072, stream,
                       ts, W0, b0, Wh, bh, Wl, bl, betaW, betab, hvec, scale,
                       y0log, out, hacc1, hacc2, hacc3, dhacc, ctrl);
}